// Round 17
// baseline (144.525 us; speedup 1.0000x reference)
//
#include <hip/hip_runtime.h>

// CSPN: 24 diffusion steps fused T=6/launch, 4 launches, NO materialized K.
// Each launch recomputes its tile's K fragment (fp32) from the ORIGINAL x
// (8.4 MB, L2-resident) - kills the gen kernel, the K write, and the
// per-launch K re-read. Fused structure = round-15 winner (4-px threads,
// c1 register carry, read2 edge pairs, stage-loads-first, (512,6)).
constexpr int B = 8, H = 512, W = 512;
constexpr int N = B * H * W;       // 2,097,152
constexpr int HW = H * W;

constexpr int TT = 32;             // output tile side
constexpr int T  = 6;              // fused steps per launch (24 = 4*6)
constexpr int XR = TT + 2 * T;     // 44: staged X region side
constexpr int XE = XR * XR;        // 1936 floats per buffer
constexpr int NG = XR / 4;         // 11 col-groups per row
constexpr int CR = XR - 2;         // 42 computed rows (xi = 1..42)
constexpr int NGT = CR * NG;       // 462 active threads
constexpr int NTH = H / TT, NTW = W / TT;   // 16 x 16
constexpr int NTILES = B * NTH * NTW;       // 2048 (div by 8 -> bijective swz)
constexpr int NT = 512;
constexpr int NF2 = XR * (XR / 2); // 968 float2 to stage

// ---------------------------------------------------------------------------
// Fused kernel: T=6 steps, 32x32 tile, X region 44x44 double-buffered in LDS.
// Thread owns 4-px group (xi, xj0..+3). K fragment computed IN-KERNEL from
// x0: aff = conv3x3(x0) + b; a = aff/sum|aff|; K0 = 1-sum a; K1..8 = a.
// Out-of-image px: K0=1, taps=0 -> copies its staged 0 (zero-pad invariant).
// ---------------------------------------------------------------------------
__global__ __launch_bounds__(NT, 6) void cspn_fused(
    const float* __restrict__ x0, const float* __restrict__ Wa,
    const float* __restrict__ ba, const float* __restrict__ xin,
    float* __restrict__ xout) {
  __shared__ __align__(16) float sBuf[64 + 2 * XE + 64];  // front/back guards
  float* sX = sBuf + 64;

  int bid = blockIdx.x;
  int wg = (bid & 7) * (NTILES / 8) + (bid >> 3);  // XCD-chunked swizzle
  int b  = wg / (NTH * NTW);
  int rr = wg % (NTH * NTW);
  int ti0 = (rr / NTW) * TT, tj0 = (rr % NTW) * TT;
  int tid = threadIdx.x;

  bool active = tid < NGT;
  int xi  = 1 + tid / NG;          // 1..42
  int xj0 = (tid % NG) * 4;        // 0,4,...,40

  const float* xb  = xin + (size_t)b * HW;
  const float* x0b = x0 + (size_t)b * HW;

  // ---- issue staging loads FIRST (latency overlaps K compute) ----
  int li0 = tid / (XR / 2), gc0 = tid - li0 * (XR / 2);
  int p1 = tid + NT;
  int li1 = p1 / (XR / 2), gc1 = p1 - li1 * (XR / 2);
  bool st1 = p1 < NF2;
  float2 sv0 = make_float2(0.f, 0.f), sv1 = make_float2(0.f, 0.f);
  {
    int gi = ti0 + li0 - T, gj = tj0 + 2 * gc0 - T;
    if ((unsigned)gi < (unsigned)H && (unsigned)gj < (unsigned)W)
      sv0 = *reinterpret_cast<const float2*>(xb + gi * W + gj);
  }
  if (st1) {
    int gi = ti0 + li1 - T, gj = tj0 + 2 * gc1 - T;
    if ((unsigned)gi < (unsigned)H && (unsigned)gj < (unsigned)W)
      sv1 = *reinterpret_cast<const float2*>(xb + gi * W + gj);
  }

  // ---- compute K fragment in fp32 for the 4 owned px ----
  float kkv[9][4];                 // [tap 0..8][px]; tap0 = center (K0)
  if (active) {
    int gi  = ti0 + xi - T;        // K row
    int gj0 = tj0 + xj0 - T;       // K col base
    // 3x6 window of ORIGINAL x (guarded scalar loads; zero-pad SAME conv)
    float rv[3][6];
#pragma unroll
    for (int r = 0; r < 3; ++r) {
      int ii = gi - 1 + r;
      bool rv_ok = (unsigned)ii < (unsigned)H;
      const float* row = x0b + (size_t)(rv_ok ? ii : 0) * W;
#pragma unroll
      for (int q = 0; q < 6; ++q) {
        int jj = gj0 - 1 + q;
        rv[r][q] = (rv_ok && (unsigned)jj < (unsigned)W) ? row[jj] : 0.f;
      }
    }
#pragma unroll
    for (int p = 0; p < 4; ++p) {
      float aff[8];
      float abs_sum = 0.f;
#pragma unroll
      for (int c = 0; c < 8; ++c) {
        float a = ba[c];
#pragma unroll
        for (int u = 0; u < 3; ++u)
#pragma unroll
          for (int q = 0; q < 3; ++q)
            a += rv[u][p + q] * Wa[c * 9 + u * 3 + q];
        aff[c] = a;
        abs_sum += fabsf(a);
      }
      float inv = 1.0f / abs_sum;
      float s = 0.f;
#pragma unroll
      for (int c = 0; c < 8; ++c) {
        aff[c] *= inv;
        s += aff[c];
      }
      bool pxv = (unsigned)gi < (unsigned)H && (unsigned)(gj0 + p) < (unsigned)W;
      kkv[0][p] = pxv ? (1.0f - s) : 1.0f;   // invalid px: copy self (0)
#pragma unroll
      for (int c = 0; c < 8; ++c) kkv[c + 1][p] = pxv ? aff[c] : 0.f;
    }
  }

  // ---- write staged values to LDS buf0; zero guards + buf1 border rows ----
  *reinterpret_cast<float2*>(sX + li0 * XR + 2 * gc0) = sv0;
  if (st1) *reinterpret_cast<float2*>(sX + li1 * XR + 2 * gc1) = sv1;
  if (tid < 64) {
    sBuf[tid] = 0.f;
    sBuf[64 + 2 * XE + tid] = 0.f;
  }
  if (tid < 2 * XR) {              // buf1 rows 0 and 43
    int r = (tid < XR) ? 0 : (XR - 1);
    int c = (tid < XR) ? tid : tid - XR;
    sX[XE + r * XR + c] = 0.f;
  }
  __syncthreads();

  // ---- T fused steps; own 4 px live in c1 ----
  int base = xi * XR + xj0;
  float4 c1;
  if (active) c1 = *reinterpret_cast<const float4*>(sX + base);
#pragma unroll
  for (int s = 0; s < T; ++s) {
    const float* Xc = sX + (s & 1) * XE;
    float* Xn = sX + (((s & 1) ^ 1)) * XE;
    if (active) {
      // edge-pair bases: offsets 0 and 5 -> ds_read2_b32
      const float* eu = Xc + base - XR - 1;
      const float* ed = Xc + base + XR - 1;
      const float* ec = Xc + base - 1;
      float l0 = eu[0], r0 = eu[5];
      float l1 = ec[0], r1 = ec[5];
      float l2 = ed[0], r2 = ed[5];
      float4 c0 = *reinterpret_cast<const float4*>(eu + 1);  // base-XR
      float4 c2 = *reinterpret_cast<const float4*>(ed + 1);  // base+XR
      float4 acc;
      acc.x = kkv[0][0] * c1.x + kkv[1][0] * l1   + kkv[2][0] * c1.y
            + kkv[3][0] * c0.x + kkv[4][0] * l0   + kkv[5][0] * c0.y
            + kkv[6][0] * c2.x + kkv[7][0] * l2   + kkv[8][0] * c2.y;
      acc.y = kkv[0][1] * c1.y + kkv[1][1] * c1.x + kkv[2][1] * c1.z
            + kkv[3][1] * c0.y + kkv[4][1] * c0.x + kkv[5][1] * c0.z
            + kkv[6][1] * c2.y + kkv[7][1] * c2.x + kkv[8][1] * c2.z;
      acc.z = kkv[0][2] * c1.z + kkv[1][2] * c1.y + kkv[2][2] * c1.w
            + kkv[3][2] * c0.z + kkv[4][2] * c0.y + kkv[5][2] * c0.w
            + kkv[6][2] * c2.z + kkv[7][2] * c2.y + kkv[8][2] * c2.w;
      acc.w = kkv[0][3] * c1.w + kkv[1][3] * c1.z + kkv[2][3] * r1
            + kkv[3][3] * c0.w + kkv[4][3] * c0.z + kkv[5][3] * r0
            + kkv[6][3] * c2.w + kkv[7][3] * c2.z + kkv[8][3] * r2;
      *reinterpret_cast<float4*>(Xn + base) = acc;
      c1 = acc;
    }
    __syncthreads();
  }

  // ---- write 32x32 tile (step-6 result is in buf0; T even) ----
  float* yb = xout + (size_t)b * HW;
  int i  = tid >> 4;               // 0..31
  int pj = (tid & 15) * 2;         // 0..30
  float2 v = *reinterpret_cast<const float2*>(sX + (i + T) * XR + (pj + T));
  *reinterpret_cast<float2*>(yb + (size_t)(ti0 + i) * W + (tj0 + pj)) = v;
}

extern "C" void kernel_launch(void* const* d_in, const int* in_sizes, int n_in,
                              void* d_out, int out_size, void* d_ws,
                              size_t ws_size, hipStream_t stream) {
  const float* x  = (const float*)d_in[0];
  const float* Wa = (const float*)d_in[1];
  const float* ba = (const float*)d_in[2];
  float* out = (float*)d_out;
  float* xa = (float*)d_ws;            // N floats ping-pong buffer

  const float* src = x;
  for (int l = 0; l < 24 / T; ++l) {   // 4 launches of 6 fused steps
    float* dst = (l & 1) ? out : xa;   // l=3 (odd) -> final lands in d_out
    cspn_fused<<<dim3(NTILES), dim3(NT), 0, stream>>>(x, Wa, ba, src, dst);
    src = dst;
  }
}

// Round 18
// 141.666 us; speedup vs baseline: 1.0202x; 1.0202x over previous
//
#include <hip/hip_runtime.h>

// CSPN: 24 diffusion steps fused T=6/launch, 4 launches, NO materialized K.
// K fragment recomputed in-kernel from the ORIGINAL x (L2-resident) into
// NINE NAMED float4 registers (kt0..kt8) - round 17's float kkv[9][4] array
// was demoted to scratch (VGPR_Count=40, dur 42us); named vectors pin it in
// registers. K-compute is branchless (clamped loads + select-0).
constexpr int B = 8, H = 512, W = 512;
constexpr int N = B * H * W;       // 2,097,152
constexpr int HW = H * W;

constexpr int TT = 32;             // output tile side
constexpr int T  = 6;              // fused steps per launch (24 = 4*6)
constexpr int XR = TT + 2 * T;     // 44: staged X region side
constexpr int XE = XR * XR;        // 1936 floats per buffer
constexpr int NG = XR / 4;         // 11 col-groups per row
constexpr int CR = XR - 2;         // 42 computed rows (xi = 1..42)
constexpr int NGT = CR * NG;       // 462 active threads
constexpr int NTH = H / TT, NTW = W / TT;   // 16 x 16
constexpr int NTILES = B * NTH * NTW;       // 2048 (div by 8 -> bijective swz)
constexpr int NT = 512;
constexpr int NF2 = XR * (XR / 2); // 968 float2 to stage

// per-pixel K: aff = conv3x3(x0)+b; a = aff/sum|aff|; kt0=1-sum a; kt1..8=a.
#define KPX(COMP, P) {                                                      \
    float aff[8]; float abs_sum = 0.f;                                      \
    _Pragma("unroll") for (int c = 0; c < 8; ++c) {                         \
      float a = ba[c];                                                      \
      _Pragma("unroll") for (int u = 0; u < 3; ++u)                         \
        _Pragma("unroll") for (int q = 0; q < 3; ++q)                       \
          a += rv[u][(P) + q] * Wa[c * 9 + u * 3 + q];                      \
      aff[c] = a; abs_sum += fabsf(a);                                      \
    }                                                                       \
    float inv = 1.0f / abs_sum; float s = 0.f;                              \
    _Pragma("unroll") for (int c = 0; c < 8; ++c) { aff[c] *= inv; s += aff[c]; } \
    bool pxv = rowv && (unsigned)(gj0 + (P)) < (unsigned)W;                 \
    kt0.COMP = pxv ? (1.0f - s) : 1.0f;                                     \
    kt1.COMP = pxv ? aff[0] : 0.f;  kt2.COMP = pxv ? aff[1] : 0.f;          \
    kt3.COMP = pxv ? aff[2] : 0.f;  kt4.COMP = pxv ? aff[3] : 0.f;          \
    kt5.COMP = pxv ? aff[4] : 0.f;  kt6.COMP = pxv ? aff[5] : 0.f;          \
    kt7.COMP = pxv ? aff[6] : 0.f;  kt8.COMP = pxv ? aff[7] : 0.f;          \
  }

__global__ __launch_bounds__(NT, 6) void cspn_fused(
    const float* __restrict__ x0, const float* __restrict__ Wa,
    const float* __restrict__ ba, const float* __restrict__ xin,
    float* __restrict__ xout) {
  __shared__ __align__(16) float sBuf[64 + 2 * XE + 64];  // front/back guards
  float* sX = sBuf + 64;

  int bid = blockIdx.x;
  int wg = (bid & 7) * (NTILES / 8) + (bid >> 3);  // XCD-chunked swizzle
  int b  = wg / (NTH * NTW);
  int rr = wg % (NTH * NTW);
  int ti0 = (rr / NTW) * TT, tj0 = (rr % NTW) * TT;
  int tid = threadIdx.x;

  bool active = tid < NGT;
  int xi  = 1 + tid / NG;          // 1..42 (inactive: up to 47, clamped use)
  int xj0 = (tid % NG) * 4;        // 0,4,...,40

  const float* xb  = xin + (size_t)b * HW;
  const float* x0b = x0 + (size_t)b * HW;

  // ---- staging loads ----
  int li0 = tid / (XR / 2), gc0 = tid - li0 * (XR / 2);
  int p1 = tid + NT;
  int li1 = p1 / (XR / 2), gc1 = p1 - li1 * (XR / 2);
  bool st1 = p1 < NF2;
  float2 sv0 = make_float2(0.f, 0.f), sv1 = make_float2(0.f, 0.f);
  {
    int gi = ti0 + li0 - T, gj = tj0 + 2 * gc0 - T;
    if ((unsigned)gi < (unsigned)H && (unsigned)gj < (unsigned)W)
      sv0 = *reinterpret_cast<const float2*>(xb + gi * W + gj);
  }
  if (st1) {
    int gi = ti0 + li1 - T, gj = tj0 + 2 * gc1 - T;
    if ((unsigned)gi < (unsigned)H && (unsigned)gj < (unsigned)W)
      sv1 = *reinterpret_cast<const float2*>(xb + gi * W + gj);
  }

  // ---- write staged values + zero guards/borders (before K math) ----
  *reinterpret_cast<float2*>(sX + li0 * XR + 2 * gc0) = sv0;
  if (st1) *reinterpret_cast<float2*>(sX + li1 * XR + 2 * gc1) = sv1;
  if (tid < 64) {
    sBuf[tid] = 0.f;
    sBuf[64 + 2 * XE + tid] = 0.f;
  }
  if (tid < 2 * XR) {              // buf1 rows 0 and 43
    int r = (tid < XR) ? 0 : (XR - 1);
    int c = (tid < XR) ? tid : tid - XR;
    sX[XE + r * XR + c] = 0.f;
  }

  // ---- branchless K fragment -> 9 named float4 (component = px) ----
  float4 kt0, kt1, kt2, kt3, kt4, kt5, kt6, kt7, kt8;
  {
    int gi  = ti0 + xi - T;        // K row
    int gj0 = tj0 + xj0 - T;       // K col base
    bool rowv_c = (unsigned)gi < (unsigned)H;  // px row validity
    // 3x6 window of ORIGINAL x; clamped addresses, select-0 (branchless)
    float rv[3][6];
#pragma unroll
    for (int r = 0; r < 3; ++r) {
      int ii = gi - 1 + r;
      bool rok = (unsigned)ii < (unsigned)H;
      int iic = min(max(ii, 0), H - 1);
      const float* row = x0b + (size_t)iic * W;
#pragma unroll
      for (int q = 0; q < 6; ++q) {
        int jj = gj0 - 1 + q;
        int jjc = min(max(jj, 0), W - 1);
        float v = row[jjc];
        rv[r][q] = (rok && (unsigned)jj < (unsigned)W) ? v : 0.f;
      }
    }
    bool rowv = rowv_c;
    KPX(x, 0) KPX(y, 1) KPX(z, 2) KPX(w, 3)
  }
  __syncthreads();

  // ---- T fused steps; own 4 px live in c1 ----
  int base = xi * XR + xj0;
  float4 c1;
  if (active) c1 = *reinterpret_cast<const float4*>(sX + base);
#pragma unroll
  for (int s = 0; s < T; ++s) {
    const float* Xc = sX + (s & 1) * XE;
    float* Xn = sX + (((s & 1) ^ 1)) * XE;
    if (active) {
      // edge-pair bases: offsets 0 and 5 -> ds_read2_b32
      const float* eu = Xc + base - XR - 1;
      const float* ed = Xc + base + XR - 1;
      const float* ec = Xc + base - 1;
      float l0 = eu[0], r0 = eu[5];
      float l1 = ec[0], r1 = ec[5];
      float l2 = ed[0], r2 = ed[5];
      float4 c0 = *reinterpret_cast<const float4*>(eu + 1);  // base-XR
      float4 c2 = *reinterpret_cast<const float4*>(ed + 1);  // base+XR
      float4 acc;
      acc.x = kt0.x * c1.x + kt1.x * l1   + kt2.x * c1.y
            + kt3.x * c0.x + kt4.x * l0   + kt5.x * c0.y
            + kt6.x * c2.x + kt7.x * l2   + kt8.x * c2.y;
      acc.y = kt0.y * c1.y + kt1.y * c1.x + kt2.y * c1.z
            + kt3.y * c0.y + kt4.y * c0.x + kt5.y * c0.z
            + kt6.y * c2.y + kt7.y * c2.x + kt8.y * c2.z;
      acc.z = kt0.z * c1.z + kt1.z * c1.y + kt2.z * c1.w
            + kt3.z * c0.z + kt4.z * c0.y + kt5.z * c0.w
            + kt6.z * c2.z + kt7.z * c2.y + kt8.z * c2.w;
      acc.w = kt0.w * c1.w + kt1.w * c1.z + kt2.w * r1
            + kt3.w * c0.w + kt4.w * c0.z + kt5.w * r0
            + kt6.w * c2.w + kt7.w * c2.z + kt8.w * r2;
      *reinterpret_cast<float4*>(Xn + base) = acc;
      c1 = acc;
    }
    __syncthreads();
  }

  // ---- write 32x32 tile (step-6 result is in buf0; T even) ----
  float* yb = xout + (size_t)b * HW;
  int i  = tid >> 4;               // 0..31
  int pj = (tid & 15) * 2;         // 0..30
  float2 v = *reinterpret_cast<const float2*>(sX + (i + T) * XR + (pj + T));
  *reinterpret_cast<float2*>(yb + (size_t)(ti0 + i) * W + (tj0 + pj)) = v;
}

extern "C" void kernel_launch(void* const* d_in, const int* in_sizes, int n_in,
                              void* d_out, int out_size, void* d_ws,
                              size_t ws_size, hipStream_t stream) {
  const float* x  = (const float*)d_in[0];
  const float* Wa = (const float*)d_in[1];
  const float* ba = (const float*)d_in[2];
  float* out = (float*)d_out;
  float* xa = (float*)d_ws;            // N floats ping-pong buffer

  const float* src = x;
  for (int l = 0; l < 24 / T; ++l) {   // 4 launches of 6 fused steps
    float* dst = (l & 1) ? out : xa;   // l=3 (odd) -> final lands in d_out
    cspn_fused<<<dim3(NTILES), dim3(NT), 0, stream>>>(x, Wa, ba, src, dst);
    src = dst;
  }
}